// Round 4
// baseline (138.475 us; speedup 1.0000x reference)
//
#include <hip/hip_runtime.h>
#include <math.h>

#define L_SEQ 192
#define H_DIM 768
#define B_SZ  8
#define NPAIR (L_SEQ * (L_SEQ + 1) / 2)   // 18528
#define MROWS (B_SZ * L_SEQ)              // 1536
#define NCOLS (2 * H_DIM)                 // 1536 (D columns: [A | C])
#define NTILE 24                           // 192/8 tile grid per side
#define NTRI  (NTILE * (NTILE + 1) / 2)    // 300 upper-tri tiles

typedef short  bf16x8  __attribute__((ext_vector_type(8)));
typedef float  f32x4   __attribute__((ext_vector_type(4)));
typedef unsigned short u16x4 __attribute__((ext_vector_type(4)));

// Decode linear upper-triangular index p -> (i, j), i<=j<Lq.
__device__ __forceinline__ void tri_decode(int p, int Lq, int& io, int& jo) {
    float tl = 2.0f * Lq + 1.0f;
    int i = (int)((tl - sqrtf(tl * tl - 8.0f * (float)p)) * 0.5f);
    if (i < 0) i = 0;
    if (i > Lq - 1) i = Lq - 1;
    while (i > 0 && i * (2 * Lq - i + 1) / 2 > p) --i;
    while (i < Lq - 1 && (i + 1) * (2 * Lq - i) / 2 <= p) ++i;
    io = i;
    jo = i + (p - i * (2 * Lq - i + 1) / 2);
}

struct HL { unsigned short h, l; };

// Split f32 into hi bf16 (RTN) + lo bf16 (RTN of residual). x ~= hi + lo.
__device__ __forceinline__ HL split_bf16(float x) {
    HL r;
    unsigned u  = __float_as_uint(x);
    unsigned rh = u + 0x7FFFu + ((u >> 16) & 1u);
    r.h = (unsigned short)(rh >> 16);
    float hf = __uint_as_float((unsigned)r.h << 16);
    float res = x - hf;
    unsigned u2 = __float_as_uint(res);
    unsigned rl = u2 + 0x7FFFu + ((u2 >> 16) & 1u);
    r.l = (unsigned short)(rl >> 16);
    return r;
}

// tanh(x) = 1 - 2/(e^{2x}+1); exp2 + rcp are single HW instructions.
__device__ __forceinline__ float fast_tanh(float x) {
    float e = __builtin_amdgcn_exp2f(x * 2.885390081777927f);  // 2*log2(e)
    return 1.0f - 2.0f * __builtin_amdgcn_rcpf(e + 1.0f);
}

// ---------------------------------------------------------------------------
// Split-bf16 MFMA GEMM (unchanged from round 3): D = [seq@W1^T | seq@W2^T]
// ---------------------------------------------------------------------------
#define LDSP 40

__global__ __launch_bounds__(256) void gemm_mfma_kernel(
    const float* __restrict__ seq,   // [1536][768]
    const float* __restrict__ W,     // [768][1536]
    float* __restrict__ D)           // [1536][1536]
{
    __shared__ unsigned short Ah[128 * LDSP], Al[128 * LDSP];
    __shared__ unsigned short Bh[128 * LDSP], Bl[128 * LDSP];

    const int t    = threadIdx.x;
    const int bn0  = blockIdx.x * 128;
    const int bm0  = blockIdx.y * 128;
    const int side = (bn0 >= H_DIM) ? 1 : 0;
    const int wrow0 = bn0 - side * H_DIM;
    const int kofs  = side * H_DIM;

    const int lane = t & 63;
    const int wave = t >> 6;
    const int wr   = wave >> 1, wc = wave & 1;
    const int l15  = lane & 15;
    const int kc   = (lane >> 4) * 8;

    const int sr = t >> 1;
    const int sk = (t & 1) * 16;

    f32x4 acc[4][4];
    #pragma unroll
    for (int a = 0; a < 4; ++a)
        #pragma unroll
        for (int b = 0; b < 4; ++b) acc[a][b] = (f32x4){0.f, 0.f, 0.f, 0.f};

    for (int k0 = 0; k0 < H_DIM; k0 += 32) {
        {
            const float* src = seq + (size_t)(bm0 + sr) * H_DIM + k0 + sk;
            unsigned short* dh = Ah + sr * LDSP + sk;
            unsigned short* dl = Al + sr * LDSP + sk;
            #pragma unroll
            for (int c = 0; c < 4; ++c) {
                float4 v = *reinterpret_cast<const float4*>(src + c * 4);
                HL sx = split_bf16(v.x), sy = split_bf16(v.y);
                HL sz = split_bf16(v.z), sw = split_bf16(v.w);
                u16x4 h = {sx.h, sy.h, sz.h, sw.h};
                u16x4 l = {sx.l, sy.l, sz.l, sw.l};
                *reinterpret_cast<u16x4*>(dh + c * 4) = h;
                *reinterpret_cast<u16x4*>(dl + c * 4) = l;
            }
        }
        {
            const float* src = W + (size_t)(wrow0 + sr) * NCOLS + kofs + k0 + sk;
            unsigned short* dh = Bh + sr * LDSP + sk;
            unsigned short* dl = Bl + sr * LDSP + sk;
            #pragma unroll
            for (int c = 0; c < 4; ++c) {
                float4 v = *reinterpret_cast<const float4*>(src + c * 4);
                HL sx = split_bf16(v.x), sy = split_bf16(v.y);
                HL sz = split_bf16(v.z), sw = split_bf16(v.w);
                u16x4 h = {sx.h, sy.h, sz.h, sw.h};
                u16x4 l = {sx.l, sy.l, sz.l, sw.l};
                *reinterpret_cast<u16x4*>(dh + c * 4) = h;
                *reinterpret_cast<u16x4*>(dl + c * 4) = l;
            }
        }
        __syncthreads();

        bf16x8 ah[4], al[4], bh[4], bl[4];
        #pragma unroll
        for (int mi = 0; mi < 4; ++mi) {
            int row = wr * 64 + mi * 16 + l15;
            ah[mi] = *reinterpret_cast<const bf16x8*>(Ah + row * LDSP + kc);
            al[mi] = *reinterpret_cast<const bf16x8*>(Al + row * LDSP + kc);
        }
        #pragma unroll
        for (int ni = 0; ni < 4; ++ni) {
            int row = wc * 64 + ni * 16 + l15;
            bh[ni] = *reinterpret_cast<const bf16x8*>(Bh + row * LDSP + kc);
            bl[ni] = *reinterpret_cast<const bf16x8*>(Bl + row * LDSP + kc);
        }

        #pragma unroll
        for (int mi = 0; mi < 4; ++mi)
            #pragma unroll
            for (int ni = 0; ni < 4; ++ni) {
                acc[mi][ni] = __builtin_amdgcn_mfma_f32_16x16x32_bf16(ah[mi], bh[ni], acc[mi][ni], 0, 0, 0);
                acc[mi][ni] = __builtin_amdgcn_mfma_f32_16x16x32_bf16(ah[mi], bl[ni], acc[mi][ni], 0, 0, 0);
                acc[mi][ni] = __builtin_amdgcn_mfma_f32_16x16x32_bf16(al[mi], bh[ni], acc[mi][ni], 0, 0, 0);
            }
        __syncthreads();
    }

    #pragma unroll
    for (int mi = 0; mi < 4; ++mi)
        #pragma unroll
        for (int ni = 0; ni < 4; ++ni) {
            int row0 = bm0 + wr * 64 + mi * 16 + (lane >> 4) * 4;
            int col  = bn0 + wc * 64 + ni * 16 + l15;
            #pragma unroll
            for (int r = 0; r < 4; ++r)
                D[(size_t)(row0 + r) * NCOLS + col] = acc[mi][ni][r];
        }
}

// ---------------------------------------------------------------------------
// Tiled combine: one block = 8x8 (i,j) pair tile for one batch.
// Thread t owns h-chunk [4t, 4t+4). Loads 8 A-chunks (+bias folded) and
// 8 C-chunks into REGISTERS (no LDS, no barrier), then writes the 64 pair
// rows. Read traffic drops 8x vs per-pair blocks; stores are nontemporal.
// ---------------------------------------------------------------------------
__global__ __launch_bounds__(192) void combine_tile_kernel(
    const float* __restrict__ D,      // [1536][1536]
    const float* __restrict__ bias,   // [768]
    float* __restrict__ out)          // [B][P][768]
{
    const int b = blockIdx.y;
    int it, jt;
    tri_decode(blockIdx.x, NTILE, it, jt);

    const int h = threadIdx.x * 4;
    const f32x4 bb = *reinterpret_cast<const f32x4*>(bias + h);
    const float* Dbase = D + (size_t)b * L_SEQ * NCOLS;

    f32x4 Ar[8], Cr[8];
    #pragma unroll
    for (int r = 0; r < 8; ++r)
        Ar[r] = *reinterpret_cast<const f32x4*>(Dbase + (size_t)(it * 8 + r) * NCOLS + h) + bb;
    #pragma unroll
    for (int r = 0; r < 8; ++r)
        Cr[r] = *reinterpret_cast<const f32x4*>(Dbase + (size_t)(jt * 8 + r) * NCOLS + H_DIM + h);

    const int diag = (it == jt);

    #pragma unroll
    for (int di = 0; di < 8; ++di) {
        const int i = it * 8 + di;
        const int prow = i * (2 * L_SEQ - i + 1) / 2 - i;   // p = prow + j
        float* orow = out + ((size_t)b * NPAIR + prow) * H_DIM + h;
        #pragma unroll
        for (int dj = 0; dj < 8; ++dj) {
            if (diag && dj < di) continue;                   // uniform skip
            const int j = jt * 8 + dj;
            f32x4 s = Ar[di] + Cr[dj];
            f32x4 o;
            o.x = fast_tanh(s.x);
            o.y = fast_tanh(s.y);
            o.z = fast_tanh(s.z);
            o.w = fast_tanh(s.w);
            __builtin_nontemporal_store(o, reinterpret_cast<f32x4*>(orow + (size_t)j * H_DIM));
        }
    }
}

// ---------------------------------------------------------------------------
// Fallback (only if ws_size too small): direct einsum, slow but correct.
// ---------------------------------------------------------------------------
__global__ __launch_bounds__(256) void naive_kernel(
    const float* __restrict__ seq,
    const float* __restrict__ W,
    const float* __restrict__ bias,
    float* __restrict__ out)
{
    const int p = blockIdx.x;
    const int b = blockIdx.y;
    int i, j;
    tri_decode(p, L_SEQ, i, j);
    const float* si = seq + ((size_t)b * L_SEQ + i) * H_DIM;
    const float* sj = seq + ((size_t)b * L_SEQ + j) * H_DIM;
    for (int h = threadIdx.x; h < H_DIM; h += 256) {
        const float* wr = W + (size_t)h * NCOLS;
        float s = bias[h];
        for (int k = 0; k < H_DIM; ++k)
            s += si[k] * wr[k] + sj[k] * wr[H_DIM + k];
        out[((size_t)b * NPAIR + p) * H_DIM + h] = tanhf(s);
    }
}

extern "C" void kernel_launch(void* const* d_in, const int* in_sizes, int n_in,
                              void* d_out, int out_size, void* d_ws, size_t ws_size,
                              hipStream_t stream) {
    const float* seq  = (const float*)d_in[0];   // [8][192][768]
    const float* W    = (const float*)d_in[1];   // [768][1536]
    const float* bias = (const float*)d_in[2];   // [768]
    float* out = (float*)d_out;                  // [8][18528][768]

    const size_t need = (size_t)MROWS * NCOLS * sizeof(float);   // 9.4 MB
    if (ws_size >= need) {
        float* D = (float*)d_ws;
        dim3 g1(NCOLS / 128, MROWS / 128);   // 12 x 12
        hipLaunchKernelGGL(gemm_mfma_kernel, g1, dim3(256), 0, stream, seq, W, D);
        dim3 g2(NTRI, B_SZ);                 // 300 x 8
        hipLaunchKernelGGL(combine_tile_kernel, g2, dim3(192), 0, stream, D, bias, out);
    } else {
        dim3 g(NPAIR, B_SZ);
        hipLaunchKernelGGL(naive_kernel, g, dim3(256), 0, stream, seq, W, bias, out);
    }
}